// Round 18
// baseline (53.607 us; speedup 1.0000x reference)
//
#include <hip/hip_runtime.h>
#include <hip/hip_fp16.h>

constexpr int R = 1024;
constexpr int C = 4096;
constexpr int N_CELLS = 8192;

constexpr unsigned LMAX    = 40u;            // per-col capacity (Poisson(6) max ~20)
constexpr unsigned SLOT    = 44u;            // e3 words per lane per window
constexpr unsigned WSTRIDE = SLOT * 64u;     // 2816
constexpr unsigned SENT    = 4096u;          // zero-sentinel LDS index
constexpr unsigned PAD_ENTRY = SENT | (SENT << 13);

// Workspace (u32 indices)
constexpr size_t WS_CURSOR = 0;              // 4096 per-col counts
constexpr size_t WS_E3     = 4096;           // 64 * 2816 pair-interleaved lists

__device__ inline __half2 h2(unsigned u) { return *reinterpret_cast<__half2*>(&u); }

__device__ inline uint2 packh4(float v0, float v1, float v2, float v3) {
    __half2 h01 = __float22half2_rn(make_float2(v0, v1));
    __half2 h23 = __float22half2_rn(make_float2(v2, v3));
    uint2 u;
    u.x = *reinterpret_cast<unsigned*>(&h01);
    u.y = *reinterpret_cast<unsigned*>(&h23);
    return u;
}

// ---- prep: write each cell's 3 entries into pair-interleaved slots.
// No padding pass -- the gather masks unwritten slots via cursor counts. ----
__global__ void fill_kernel(const int* __restrict__ i0, const int* __restrict__ i1,
                            const int* __restrict__ i2, unsigned* __restrict__ cursor,
                            unsigned* __restrict__ e3) {
    const int n = blockIdx.x * 256 + threadIdx.x;
    if (n < N_CELLS) {
        const unsigned a = (unsigned)i0[n], b = (unsigned)i1[n], c = (unsigned)i2[n];
        auto put = [&](unsigned col, unsigned oa, unsigned ob) {
            const unsigned i = atomicAdd(&cursor[col], 1u);
            if (i < LMAX)
                e3[(col >> 6) * WSTRIDE + (i >> 1) * 128u + (col & 63u) * 2u + (i & 1u)]
                    = oa | (ob << 13);
        };
        put(a, b, c);
        put(b, a, c);
        put(c, a, b);
    }
}

// ---- main (R16 + hoisted window preambles): one block per r, 512 threads,
// 32 KiB+8 LDS -> 4 blocks/CU. All 8 windows' trip counts computed up front
// (coalesced cursor loads + shfl-max), removing 8 serial pipeline restarts. ----
__global__ __launch_bounds__(512, 8) void gather_kernel(
    const float* __restrict__ in,
    const unsigned* __restrict__ cursor,
    const unsigned* __restrict__ e3,
    float* __restrict__ out)
{
    __shared__ uint2 sh[C + 1];   // 32776 B; sh[4096] = zero sentinel

    const int r = blockIdx.x;
    const int t = threadIdx.x;

    const float* __restrict__ p0r = in + ((size_t)0 * R + r) * C;
    const float* __restrict__ p1r = in + ((size_t)1 * R + r) * C;
    const float* __restrict__ p2r = in + ((size_t)2 * R + r) * C;
    const float* __restrict__ p3r = in + ((size_t)3 * R + r) * C;

    #pragma unroll
    for (int j = 0; j < 2; ++j) {
        const int c = t * 8 + j * 4;
        const float4 a = *reinterpret_cast<const float4*>(p0r + c);
        const float4 b = *reinterpret_cast<const float4*>(p1r + c);
        const float4 d = *reinterpret_cast<const float4*>(p2r + c);
        const float4 g = *reinterpret_cast<const float4*>(p3r + c);
        sh[c + 0] = packh4(a.x, b.x, d.x, g.x);
        sh[c + 1] = packh4(a.y, b.y, d.y, g.y);
        sh[c + 2] = packh4(a.z, b.z, d.z, g.z);
        sh[c + 3] = packh4(a.w, b.w, d.w, g.w);
    }
    if (t == 0) sh[SENT] = make_uint2(0u, 0u);

    const unsigned wave = (unsigned)t >> 6;
    const unsigned lane = (unsigned)t & 63u;

    // ---- hoisted preamble: per-lane counts + wave-uniform trip counts for
    // all 8 windows (overlaps the staging loads above; no LDS dependency) ----
    unsigned cnts[8];
    unsigned nprs[8];
    #pragma unroll
    for (int k = 0; k < 8; ++k) {
        const unsigned c = (wave * 8u + (unsigned)k) * 64u + lane;
        unsigned v = cursor[c];
        cnts[k] = v > LMAX ? LMAX : v;
    }
    #pragma unroll
    for (int k = 0; k < 8; ++k) {
        unsigned m = cnts[k];
        #pragma unroll
        for (int o = 1; o < 64; o <<= 1)
            m = max(m, (unsigned)__shfl_xor((int)m, o, 64));
        nprs[k] = (m + 1u) >> 1;
    }
    __syncthreads();

    #pragma unroll
    for (int k = 0; k < 8; ++k) {
        const unsigned w = wave * 8u + (unsigned)k;
        const unsigned c = w * 64u + lane;
        const unsigned cnt = cnts[k];
        const unsigned npairs = nprs[k];

        const uint2* __restrict__ lst2 =
            reinterpret_cast<const uint2*>(e3 + w * WSTRIDE) + lane;

        // mask a pair-word: entry 2j -> .x, entry 2j+1 -> .y
        auto mword = [&](uint2 v, unsigned j) -> uint2 {
            v.x = (2u * j      < cnt) ? v.x : PAD_ENTRY;
            v.y = (2u * j + 1u < cnt) ? v.y : PAD_ENTRY;
            return v;
        };

        __half2 accA01 = __float2half2_rn(0.f), accA23 = accA01;
        __half2 accB01 = accA01, accB23 = accA01;

        uint2 pc = mword(lst2[0], 0u);
        uint2 pn = mword(lst2[64], 1u);
        uint2 A0 = sh[pc.x & 8191u], B0 = sh[pc.x >> 13];
        uint2 A1 = sh[pc.y & 8191u], B1 = sh[pc.y >> 13];

        for (unsigned j = 0; j < npairs; ++j) {
            const uint2 p2w = mword(lst2[(j + 2) * 64u], j + 2u);
            const uint2 A0n = sh[pn.x & 8191u], B0n = sh[pn.x >> 13];
            const uint2 A1n = sh[pn.y & 8191u], B1n = sh[pn.y >> 13];

            accA01 = __hfma2(h2(A0.x), h2(B0.x), accA01);
            accA23 = __hfma2(h2(A0.y), h2(B0.y), accA23);
            accB01 = __hfma2(h2(A1.x), h2(B1.x), accB01);
            accB23 = __hfma2(h2(A1.y), h2(B1.y), accB23);

            pc = pn; pn = p2w;
            A0 = A0n; B0 = B0n; A1 = A1n; B1 = B1n;
        }

        const __half2 s01 = __hadd2(accA01, accB01);
        const __half2 s23 = __hadd2(accA23, accB23);
        const float2 f01 = __half22float2(s01);
        const float2 f23 = __half22float2(s23);

        const uint2 ownp = sh[c];
        const float2 o01 = __half22float2(h2(ownp.x));
        const float2 o23 = __half22float2(h2(ownp.y));

        __builtin_nontemporal_store(o01.x * f01.x, out + ((size_t)0 * R + r) * C + c);
        __builtin_nontemporal_store(o01.y * f01.y, out + ((size_t)1 * R + r) * C + c);
        __builtin_nontemporal_store(o23.x * f23.x, out + ((size_t)2 * R + r) * C + c);
        __builtin_nontemporal_store(o23.y * f23.y, out + ((size_t)3 * R + r) * C + c);
        __builtin_nontemporal_store(f01.x,         out + ((size_t)4 * R + r) * C + c);
        __builtin_nontemporal_store(f01.y,         out + ((size_t)5 * R + r) * C + c);
        __builtin_nontemporal_store(f23.x,         out + ((size_t)6 * R + r) * C + c);
        __builtin_nontemporal_store(f23.y,         out + ((size_t)7 * R + r) * C + c);
    }
}

extern "C" void kernel_launch(void* const* d_in, const int* in_sizes, int n_in,
                              void* d_out, int out_size, void* d_ws, size_t ws_size,
                              hipStream_t stream) {
    const float* in   = (const float*)d_in[0];
    const int*   idx0 = (const int*)d_in[1];
    const int*   idx1 = (const int*)d_in[2];
    const int*   idx2 = (const int*)d_in[3];
    float* out = (float*)d_out;

    unsigned* ws     = (unsigned*)d_ws;
    unsigned* cursor = ws + WS_CURSOR;
    unsigned* e3     = ws + WS_E3;

    hipMemsetAsync(cursor, 0, C * sizeof(unsigned), stream);

    fill_kernel<<<dim3(N_CELLS / 256), dim3(256), 0, stream>>>(idx0, idx1, idx2, cursor, e3);
    gather_kernel<<<dim3(R), dim3(512), 0, stream>>>(in, cursor, e3, out);
}

// Round 19
// 51.658 us; speedup vs baseline: 1.0377x; 1.0377x over previous
//
#include <hip/hip_runtime.h>
#include <hip/hip_fp16.h>

constexpr int R = 1024;
constexpr int C = 4096;
constexpr int N_CELLS = 8192;

constexpr unsigned LMAX    = 40u;            // per-col capacity (Poisson(6) max ~20)
constexpr unsigned SLOT    = 44u;            // e3 words per lane per window
constexpr unsigned WSTRIDE = SLOT * 64u;     // 2816
constexpr unsigned SENT    = 4096u;          // zero-sentinel LDS index
constexpr unsigned PAD_ENTRY = SENT | (SENT << 13);

// Workspace (u32 indices)
constexpr size_t WS_CURSOR = 0;              // 4096 per-col counts
constexpr size_t WS_E3     = 4096;           // 64 * 2816 pair-interleaved lists

__device__ inline __half2 h2(unsigned u) { return *reinterpret_cast<__half2*>(&u); }

__device__ inline uint2 packh4(float v0, float v1, float v2, float v3) {
    __half2 h01 = __float22half2_rn(make_float2(v0, v1));
    __half2 h23 = __float22half2_rn(make_float2(v2, v3));
    uint2 u;
    u.x = *reinterpret_cast<unsigned*>(&h01);
    u.y = *reinterpret_cast<unsigned*>(&h23);
    return u;
}

// ---- prep: write each cell's 3 entries into pair-interleaved slots.
// No padding pass -- the gather masks unwritten slots via cursor counts. ----
__global__ void fill_kernel(const int* __restrict__ i0, const int* __restrict__ i1,
                            const int* __restrict__ i2, unsigned* __restrict__ cursor,
                            unsigned* __restrict__ e3) {
    const int n = blockIdx.x * 256 + threadIdx.x;
    if (n < N_CELLS) {
        const unsigned a = (unsigned)i0[n], b = (unsigned)i1[n], c = (unsigned)i2[n];
        auto put = [&](unsigned col, unsigned oa, unsigned ob) {
            const unsigned i = atomicAdd(&cursor[col], 1u);
            if (i < LMAX)
                e3[(col >> 6) * WSTRIDE + (i >> 1) * 128u + (col & 63u) * 2u + (i & 1u)]
                    = oa | (ob << 13);
        };
        put(a, b, c);
        put(b, a, c);
        put(c, a, b);
    }
}

// ---- main (R16, champion): one block per r, 512 threads, 32 KiB+8 LDS ->
// 4 blocks/CU. Wave computes its window's trip count from cursor via
// shfl-max; list words are masked to PAD_ENTRY before decode so unwritten
// slots contribute exactly zero (sh[4096] = 0 sentinel). ----
__global__ __launch_bounds__(512, 8) void gather_kernel(
    const float* __restrict__ in,
    const unsigned* __restrict__ cursor,
    const unsigned* __restrict__ e3,
    float* __restrict__ out)
{
    __shared__ uint2 sh[C + 1];   // 32776 B; sh[4096] = zero sentinel

    const int r = blockIdx.x;
    const int t = threadIdx.x;

    const float* __restrict__ p0r = in + ((size_t)0 * R + r) * C;
    const float* __restrict__ p1r = in + ((size_t)1 * R + r) * C;
    const float* __restrict__ p2r = in + ((size_t)2 * R + r) * C;
    const float* __restrict__ p3r = in + ((size_t)3 * R + r) * C;

    #pragma unroll
    for (int j = 0; j < 2; ++j) {
        const int c = t * 8 + j * 4;
        const float4 a = *reinterpret_cast<const float4*>(p0r + c);
        const float4 b = *reinterpret_cast<const float4*>(p1r + c);
        const float4 d = *reinterpret_cast<const float4*>(p2r + c);
        const float4 g = *reinterpret_cast<const float4*>(p3r + c);
        sh[c + 0] = packh4(a.x, b.x, d.x, g.x);
        sh[c + 1] = packh4(a.y, b.y, d.y, g.y);
        sh[c + 2] = packh4(a.z, b.z, d.z, g.z);
        sh[c + 3] = packh4(a.w, b.w, d.w, g.w);
    }
    if (t == 0) sh[SENT] = make_uint2(0u, 0u);
    __syncthreads();

    const unsigned wave = (unsigned)t >> 6;
    const unsigned lane = (unsigned)t & 63u;

    #pragma unroll
    for (int k = 0; k < 8; ++k) {
        const unsigned w = wave * 8u + (unsigned)k;
        const unsigned c = w * 64u + lane;

        // per-lane entry count; wave-max -> uniform trip count
        unsigned cnt = cursor[c];
        if (cnt > LMAX) cnt = LMAX;
        unsigned m = cnt;
        #pragma unroll
        for (int o = 1; o < 64; o <<= 1)
            m = max(m, (unsigned)__shfl_xor((int)m, o, 64));
        const unsigned npairs = (m + 1u) >> 1;

        const uint2* __restrict__ lst2 =
            reinterpret_cast<const uint2*>(e3 + w * WSTRIDE) + lane;

        // mask a pair-word: entry 2j -> .x, entry 2j+1 -> .y
        auto mword = [&](uint2 v, unsigned j) -> uint2 {
            v.x = (2u * j      < cnt) ? v.x : PAD_ENTRY;
            v.y = (2u * j + 1u < cnt) ? v.y : PAD_ENTRY;
            return v;
        };

        __half2 accA01 = __float2half2_rn(0.f), accA23 = accA01;
        __half2 accB01 = accA01, accB23 = accA01;

        uint2 pc = mword(lst2[0], 0u);
        uint2 pn = mword(lst2[64], 1u);
        uint2 A0 = sh[pc.x & 8191u], B0 = sh[pc.x >> 13];
        uint2 A1 = sh[pc.y & 8191u], B1 = sh[pc.y >> 13];

        for (unsigned j = 0; j < npairs; ++j) {
            const uint2 p2w = mword(lst2[(j + 2) * 64u], j + 2u);
            const uint2 A0n = sh[pn.x & 8191u], B0n = sh[pn.x >> 13];
            const uint2 A1n = sh[pn.y & 8191u], B1n = sh[pn.y >> 13];

            accA01 = __hfma2(h2(A0.x), h2(B0.x), accA01);
            accA23 = __hfma2(h2(A0.y), h2(B0.y), accA23);
            accB01 = __hfma2(h2(A1.x), h2(B1.x), accB01);
            accB23 = __hfma2(h2(A1.y), h2(B1.y), accB23);

            pc = pn; pn = p2w;
            A0 = A0n; B0 = B0n; A1 = A1n; B1 = B1n;
        }

        const __half2 s01 = __hadd2(accA01, accB01);
        const __half2 s23 = __hadd2(accA23, accB23);
        const float2 f01 = __half22float2(s01);
        const float2 f23 = __half22float2(s23);

        const uint2 ownp = sh[c];
        const float2 o01 = __half22float2(h2(ownp.x));
        const float2 o23 = __half22float2(h2(ownp.y));

        __builtin_nontemporal_store(o01.x * f01.x, out + ((size_t)0 * R + r) * C + c);
        __builtin_nontemporal_store(o01.y * f01.y, out + ((size_t)1 * R + r) * C + c);
        __builtin_nontemporal_store(o23.x * f23.x, out + ((size_t)2 * R + r) * C + c);
        __builtin_nontemporal_store(o23.y * f23.y, out + ((size_t)3 * R + r) * C + c);
        __builtin_nontemporal_store(f01.x,         out + ((size_t)4 * R + r) * C + c);
        __builtin_nontemporal_store(f01.y,         out + ((size_t)5 * R + r) * C + c);
        __builtin_nontemporal_store(f23.x,         out + ((size_t)6 * R + r) * C + c);
        __builtin_nontemporal_store(f23.y,         out + ((size_t)7 * R + r) * C + c);
    }
}

extern "C" void kernel_launch(void* const* d_in, const int* in_sizes, int n_in,
                              void* d_out, int out_size, void* d_ws, size_t ws_size,
                              hipStream_t stream) {
    const float* in   = (const float*)d_in[0];
    const int*   idx0 = (const int*)d_in[1];
    const int*   idx1 = (const int*)d_in[2];
    const int*   idx2 = (const int*)d_in[3];
    float* out = (float*)d_out;

    unsigned* ws     = (unsigned*)d_ws;
    unsigned* cursor = ws + WS_CURSOR;
    unsigned* e3     = ws + WS_E3;

    hipMemsetAsync(cursor, 0, C * sizeof(unsigned), stream);

    fill_kernel<<<dim3(N_CELLS / 256), dim3(256), 0, stream>>>(idx0, idx1, idx2, cursor, e3);
    gather_kernel<<<dim3(R), dim3(512), 0, stream>>>(in, cursor, e3, out);
}